// Round 3
// baseline (49.348 us; speedup 1.0000x reference)
//
#include <hip/hip_runtime.h>
#include <hip/hip_fp16.h>

#define NTH 512

typedef __attribute__((ext_vector_type(4))) _Float16 f16x4;
typedef __attribute__((ext_vector_type(8))) _Float16 f16x8;
typedef __attribute__((ext_vector_type(4))) float f32x4;

union U16x8 { uint4 u; f16x8 h; };
union U16x4 { uint2 u; f16x4 h; };

static __device__ __forceinline__ unsigned pk2(float a, float b) {
    union { __half2 h; unsigned u; } v;
    v.h = __floats2half2_rn(a, b);
    return v.u;
}
// two 8B LDS loads -> one f16x8 fragment (rows not 16B aligned)
static __device__ __forceinline__ f16x8 ld2b64(const _Float16* p) {
    uint2 lo = *reinterpret_cast<const uint2*>(p);
    uint2 hi = *reinterpret_cast<const uint2*>(p + 4);
    U16x8 r; r.u = make_uint4(lo.x, lo.y, hi.x, hi.y);
    return r.h;
}

// ---------------- prep: WaT f16[192][64] (q cols pre-scaled 0.25), WpT f16[64][64] ----------------
__global__ void csa_prep(const float* __restrict__ Wa, const float* __restrict__ Wp,
                         _Float16* __restrict__ waT, _Float16* __restrict__ wpT) {
    int i = blockIdx.x * blockDim.x + threadIdx.x;   // 0..16383
    if (i < 192 * 64) {
        int c = i >> 6, k = i & 63;
        float v = Wa[k * 192 + c];
        if (c < 64) v *= 0.25f;                      // fold head_dim^-0.5 into q
        waT[i] = (_Float16)v;
    } else {
        int j = i - 192 * 64;                        // 0..4095
        int c = j >> 6, k = j & 63;
        wpT[j] = (_Float16)Wp[k * 64 + c];
    }
}

// LDS map (f16 units):
//   sO [128][76] : 0      .. 9728    (19456 B)
//   sQ [4][2560] : 9728   .. 19968   (stride 20 per row)
//   sK [4][2560] : 19968  .. 30208
//   sV [4][2112] : 30208  .. 38656   (V^T: [d][s], row stride 132)
#define LDS_BYTES 77312

// one (head, t-tile N) attention unit; full softmax; all MFMA K=16
template<int N>
static __device__ __forceinline__ void attn_unit(const _Float16* Qh, const _Float16* Kh,
                                                 const _Float16* Vh, _Float16* sO,
                                                 int lc, int lg, int h) {
    constexpr int NT = N + 1;                 // live s-tiles
    f16x4 qf = *reinterpret_cast<const f16x4*>(Qh + (16 * N + lc) * 20 + 4 * lg);

    float pv[NT * 4];
    #pragma unroll
    for (int st = 0; st < NT; ++st) {
        f16x4 kf = *reinterpret_cast<const f16x4*>(Kh + (16 * st + lc) * 20 + 4 * lg);
        f32x4 z = (f32x4){0.f, 0.f, 0.f, 0.f};
        f32x4 sf = __builtin_amdgcn_mfma_f32_16x16x16f16(kf, qf, z, 0, 0, 0);
        if (st == N) {              // diagonal tile: mask s_local > t_local
            #pragma unroll
            for (int j = 0; j < 4; ++j)
                pv[4 * st + j] = (4 * lg + j <= lc) ? sf[j] : -1e30f;
        } else {
            #pragma unroll
            for (int j = 0; j < 4; ++j) pv[4 * st + j] = sf[j];
        }
    }

    // max (tree), lane-local then across lg via shfl
    float tm[NT];
    #pragma unroll
    for (int st = 0; st < NT; ++st)
        tm[st] = fmaxf(fmaxf(pv[4 * st], pv[4 * st + 1]), fmaxf(pv[4 * st + 2], pv[4 * st + 3]));
    #pragma unroll
    for (int s = 1; s < NT; s *= 2)
        #pragma unroll
        for (int i = 0; i + s < NT; i += 2 * s) tm[i] = fmaxf(tm[i], tm[i + s]);
    float m = tm[0];
    m = fmaxf(m, __shfl_xor(m, 16));
    m = fmaxf(m, __shfl_xor(m, 32));

    // exp + sum
    float l = 0.f;
    #pragma unroll
    for (int i = 0; i < NT * 4; ++i) { pv[i] = __expf(pv[i] - m); l += pv[i]; }
    l += __shfl_xor(l, 16);
    l += __shfl_xor(l, 32);

    // PV: P^T D-frag layout == K=16 B-frag layout -> direct feed
    f32x4 Ofr = (f32x4){0.f, 0.f, 0.f, 0.f};
    #pragma unroll
    for (int st = 0; st < NT; ++st) {
        f16x4 vf = *reinterpret_cast<const f16x4*>(Vh + lc * 132 + 16 * st + 4 * lg);
        U16x4 pb;
        pb.u = make_uint2(pk2(pv[4 * st], pv[4 * st + 1]), pk2(pv[4 * st + 2], pv[4 * st + 3]));
        Ofr = __builtin_amdgcn_mfma_f32_16x16x16f16(vf, pb.h, Ofr, 0, 0, 0);
    }

    float inv = 1.0f / l;
    uint2 ou = make_uint2(pk2(Ofr[0] * inv, Ofr[1] * inv), pk2(Ofr[2] * inv, Ofr[3] * inv));
    *reinterpret_cast<uint2*>(sO + (16 * N + lc) * 76 + 16 * h + 4 * lg) = ou;
}

__global__ __launch_bounds__(NTH, 4)
void csa_mfma(const float* __restrict__ x, const _Float16* __restrict__ waT,
              const float* __restrict__ ba, const _Float16* __restrict__ wpT,
              const float* __restrict__ bp, float* __restrict__ out)
{
    extern __shared__ __align__(16) char lds[];
    _Float16* sO = reinterpret_cast<_Float16*>(lds);
    _Float16* sQ = reinterpret_cast<_Float16*>(lds) + 9728;
    _Float16* sK = reinterpret_cast<_Float16*>(lds) + 19968;
    _Float16* sV = reinterpret_cast<_Float16*>(lds) + 30208;

    const int b    = blockIdx.x;
    const int tid  = threadIdx.x;
    const int lane = tid & 63;
    const int w    = tid >> 6;    // wave 0..7
    const int lc   = lane & 15;
    const int lg   = lane >> 4;   // 0..3

    const float* __restrict__ xb = x + (size_t)b * 8192;

    // ================= Phase B: qkv = x @ Wa + ba =================
    // wave w owns t-tile w; A-frag (x rows) from global; B-frags from WaT (L2-hot).
    f16x8 afr[2];
    {
        const float* xr = xb + (16 * w + lc) * 64 + 8 * lg;
        #pragma unroll
        for (int kk = 0; kk < 2; ++kk) {
            float4 a = *reinterpret_cast<const float4*>(xr + 32 * kk);
            float4 c = *reinterpret_cast<const float4*>(xr + 32 * kk + 4);
            U16x8 u;
            u.u = make_uint4(pk2(a.x, a.y), pk2(a.z, a.w), pk2(c.x, c.y), pk2(c.z, c.w));
            afr[kk] = u.h;
        }
    }

    f32x4 acc[12];
    #pragma unroll
    for (int n = 0; n < 12; ++n) {
        float bias = ba[16 * n + lc];
        if (n < 4) bias *= 0.25f;             // q bias scaled like q weights
        acc[n] = (f32x4){bias, bias, bias, bias};
    }
    #pragma unroll
    for (int kk = 0; kk < 2; ++kk) {
        #pragma unroll
        for (int n = 0; n < 12; ++n) {
            f16x8 bfr = *reinterpret_cast<const f16x8*>(waT + (16 * n + lc) * 64 + 32 * kk + 8 * lg);
            acc[n] = __builtin_amdgcn_mfma_f32_16x16x32_f16(afr[kk], bfr, acc[n], 0, 0, 0);
        }
    }

    // scatter q/k/v (D-frag: col c = 16n+lc, row t = 16w+4lg+j)
    #pragma unroll
    for (int n = 0; n < 12; ++n) {
        const int h = n & 3;
        const int kind = n >> 2;  // 0=q 1=k 2=v
        if (kind == 0) {
            #pragma unroll
            for (int j = 0; j < 4; ++j)
                sQ[h * 2560 + (16 * w + 4 * lg + j) * 20 + lc] = (_Float16)acc[n][j];
        } else if (kind == 1) {
            #pragma unroll
            for (int j = 0; j < 4; ++j)
                sK[h * 2560 + (16 * w + 4 * lg + j) * 20 + lc] = (_Float16)acc[n][j];
        } else {
            uint2 u = make_uint2(pk2(acc[n][0], acc[n][1]), pk2(acc[n][2], acc[n][3]));
            *reinterpret_cast<uint2*>(sV + h * 2112 + lc * 132 + 16 * w + 4 * lg) = u;
        }
    }
    __syncthreads();

    // ================= Phase C: causal attention, K=16 MFMA, full softmax =================
    {
        const int h = w & 3;
        const _Float16* Qh = sQ + h * 2560;
        const _Float16* Kh = sK + h * 2560;
        const _Float16* Vh = sV + h * 2112;
        if ((w >> 2) == 0) {       // units balanced: 1+4+5+8 = 18 live s-tiles
            attn_unit<0>(Qh, Kh, Vh, sO, lc, lg, h);
            attn_unit<3>(Qh, Kh, Vh, sO, lc, lg, h);
            attn_unit<4>(Qh, Kh, Vh, sO, lc, lg, h);
            attn_unit<7>(Qh, Kh, Vh, sO, lc, lg, h);
        } else {                   // 2+3+6+7 = 18
            attn_unit<1>(Qh, Kh, Vh, sO, lc, lg, h);
            attn_unit<2>(Qh, Kh, Vh, sO, lc, lg, h);
            attn_unit<5>(Qh, Kh, Vh, sO, lc, lg, h);
            attn_unit<6>(Qh, Kh, Vh, sO, lc, lg, h);
        }
    }

    // preload phase-D A-frags + bias while waiting at the barrier
    const int m  = w >> 1;
    const int n0 = 4 * (w & 1);
    f16x8 af[2];
    #pragma unroll
    for (int kk = 0; kk < 2; ++kk)
        af[kk] = *reinterpret_cast<const f16x8*>(wpT + (16 * m + lc) * 64 + 32 * kk + 8 * lg);
    float4 bia = *reinterpret_cast<const float4*>(bp + 16 * m + 4 * lg);
    __syncthreads();

    // ================= Phase D: out = O @ Wp + bp =================
    {
        f32x4 dacc[4];
        #pragma unroll
        for (int i = 0; i < 4; ++i) dacc[i] = (f32x4){bia.x, bia.y, bia.z, bia.w};

        #pragma unroll
        for (int kk = 0; kk < 2; ++kk) {
            #pragma unroll
            for (int i = 0; i < 4; ++i) {
                f16x8 bf = ld2b64(sO + (16 * (n0 + i) + lc) * 76 + 32 * kk + 8 * lg);
                dacc[i] = __builtin_amdgcn_mfma_f32_16x16x32_f16(af[kk], bf, dacc[i], 0, 0, 0);
            }
        }
        #pragma unroll
        for (int i = 0; i < 4; ++i) {
            int t = 16 * (n0 + i) + lc;
            *reinterpret_cast<float4*>(out + (size_t)b * 8192 + t * 64 + 16 * m + 4 * lg) =
                make_float4(dacc[i][0], dacc[i][1], dacc[i][2], dacc[i][3]);
        }
    }
}

extern "C" void kernel_launch(void* const* d_in, const int* in_sizes, int n_in,
                              void* d_out, int out_size, void* d_ws, size_t ws_size,
                              hipStream_t stream) {
    const float* x  = (const float*)d_in[0];
    const float* Wa = (const float*)d_in[1];
    const float* ba = (const float*)d_in[2];
    const float* Wp = (const float*)d_in[3];
    const float* bp = (const float*)d_in[4];
    float* out = (float*)d_out;

    _Float16* waT = (_Float16*)d_ws;                 // 24576 B
    _Float16* wpT = (_Float16*)((char*)d_ws + 24576); // 8192 B

    const int B = in_sizes[0] / 8192;  // 1024

    csa_prep<<<64, 256, 0, stream>>>(Wa, Wp, waT, wpT);

    (void)hipFuncSetAttribute(reinterpret_cast<const void*>(csa_mfma),
                              hipFuncAttributeMaxDynamicSharedMemorySize,
                              (int)LDS_BYTES);
    csa_mfma<<<B, NTH, LDS_BYTES, stream>>>(x, waT, ba, wpT, bp, out);
}